// Round 10
// baseline (113.432 us; speedup 1.0000x reference)
//
#include <hip/hip_runtime.h>
#include <hip/hip_bf16.h>

#define B_    64
#define S_    513
#define T_    512
#define H_    1024
#define OUT_  128

#define BM 32
#define BN 128
#define BK 32
#define NKT (H_ / BK)   // 32

#define ACS 272    // A LDS chunk stride (ushorts): 544 B -> +8 banks per ksl
#define BCS 1040   // B LDS chunk stride (ushorts): 2080 B -> +8 banks per ksl

typedef __attribute__((ext_vector_type(8))) short short8_t;
typedef __attribute__((ext_vector_type(4))) float f32x4;

__device__ inline ushort f2bf(float f) {
    union { float f; unsigned u; } x; x.f = f;
    unsigned r = x.u + 0x7fffu + ((x.u >> 16) & 1u);   // RNE
    return (ushort)(r >> 16);
}
__device__ inline float bf2f(ushort u) {
    union { unsigned u; float f; } x; x.u = (unsigned)u << 16; return x.f;
}
// 4 fp32 -> 4 bf16 (RNE) via HW pack-convert
__device__ inline uint2 cvt4(const float4& v) {
    uint2 r;
    asm("v_cvt_pk_bf16_f32 %0, %1, %2" : "=v"(r.x) : "v"(v.x), "v"(v.y));
    asm("v_cvt_pk_bf16_f32 %0, %1, %2" : "=v"(r.y) : "v"(v.z), "v"(v.w));
    return r;
}

// ---------------------------------------------------------------------------
// Kernel 0: Wt[o][k] = bf16(W[k][o])  (256 KB, stays L2-resident)
// ---------------------------------------------------------------------------
__global__ __launch_bounds__(256) void wt_kernel(
    const float* __restrict__ W, ushort* __restrict__ Wt)
{
    __shared__ ushort tile[64][65];
    int k0 = blockIdx.x * 64, o0 = blockIdx.y * 64;
    int tid = threadIdx.x;
#pragma unroll
    for (int p = 0; p < 16; ++p) {
        int idx = tid + p * 256;
        int r = idx >> 6, c = idx & 63;
        tile[r][c] = f2bf(W[(size_t)(k0 + r) * OUT_ + o0 + c]);
    }
    __syncthreads();
#pragma unroll
    for (int p = 0; p < 16; ++p) {
        int idx = tid + p * 256;
        int c = idx >> 6, r = idx & 63;
        Wt[(size_t)(o0 + c) * H_ + k0 + r] = tile[r][c];
    }
}

// ---------------------------------------------------------------------------
// Kernel 1: logits(bf16) = bf16(x) @ bf16(Wt^T), raw (bias in merge).
// 32(T) x 128(OUT) tile -> grid 1024 = 4 blocks/CU, 256 thr = 4 waves,
// wave tile 32x32 (2A x 2B frags). k-major padded LDS (conflict-free b128),
// register prefetch depth 2 (load k+3 issued in iter k), LDS double buffer,
// one barrier per K-iter.
// ---------------------------------------------------------------------------
__global__ __launch_bounds__(256, 4) void gemm_kernel(
    const float* __restrict__ hs, const ushort* __restrict__ Wt,
    ushort* __restrict__ logits)
{
    __shared__ __align__(16) ushort As[2][4 * ACS];   // 4.3 KB
    __shared__ __align__(16) ushort Bs[2][4 * BCS];   // 16.6 KB

    int blk = blockIdx.x;
    int b   = blk >> 4;
    int t0  = (blk & 15) * BM;
    int tid = threadIdx.x;
    int lane = tid & 63;
    int w    = tid >> 6;            // wave: cols [w*32, w*32+32)
    int l15  = lane & 15, ksl = lane >> 4;

    // A staging: thread = one float4 (4 k-elems) of one row
    int arow = tid >> 3, ac2 = tid & 7;
    const float* aptr = hs + ((size_t)(b * S_ + 1 + t0 + arow)) * H_ + ac2 * 4;
    int wAo = (ac2 >> 1) * ACS + arow * 8 + (ac2 & 1) * 4;

    // B staging: thread = 32 B (two 16B chunks) of one Wt row
    int brow = tid >> 1, bc = (tid & 1) * 2;
    const ushort* bptr = Wt + (size_t)brow * H_ + bc * 8;
    int wBo0 = bc * BCS + brow * 8;
    int wBo1 = wBo0 + BCS;

    // fragment read offsets
    int rAo[2], rBo[2];
#pragma unroll
    for (int fm = 0; fm < 2; ++fm) rAo[fm] = ksl * ACS + (fm * 16 + l15) * 8;
#pragma unroll
    for (int fn = 0; fn < 2; ++fn)
        rBo[fn] = ksl * BCS + (w * 32 + fn * 16 + l15) * 8;

    f32x4 acc[2][2];
#pragma unroll
    for (int fm = 0; fm < 2; ++fm)
#pragma unroll
        for (int fn = 0; fn < 2; ++fn) acc[fm][fn] = (f32x4){0.f, 0.f, 0.f, 0.f};

    float4 ra[2];
    int4   rb0[2], rb1[2];

    auto LD = [&](int s, int kt) {
        const float* ap = aptr + kt * BK;
        ra[s]  = *reinterpret_cast<const float4*>(ap);
        const ushort* bp = bptr + kt * BK;
        rb0[s] = *reinterpret_cast<const int4*>(bp);
        rb1[s] = *reinterpret_cast<const int4*>(bp + 8);
    };
    auto WR = [&](int nb, int s) {
        *reinterpret_cast<uint2*>(&As[nb][wAo]) = cvt4(ra[s]);
        *reinterpret_cast<int4*>(&Bs[nb][wBo0]) = rb0[s];
        *reinterpret_cast<int4*>(&Bs[nb][wBo1]) = rb1[s];
    };
    auto COMPUTE = [&](int cb) {
        short8_t af[2], bf[2];
#pragma unroll
        for (int fm = 0; fm < 2; ++fm)
            af[fm] = *reinterpret_cast<const short8_t*>(&As[cb][rAo[fm]]);
#pragma unroll
        for (int fn = 0; fn < 2; ++fn)
            bf[fn] = *reinterpret_cast<const short8_t*>(&Bs[cb][rBo[fn]]);
#pragma unroll
        for (int fm = 0; fm < 2; ++fm)
#pragma unroll
            for (int fn = 0; fn < 2; ++fn)
                acc[fm][fn] = __builtin_amdgcn_mfma_f32_16x16x32_bf16(
                    af[fm], bf[fn], acc[fm][fn], 0, 0, 0);
    };

    // prologue: k0,k1 in regs; k0 staged; k2 into slot 0
    LD(0, 0); LD(1, 1);
    WR(0, 0);
    __syncthreads();
    LD(0, 2);

    for (int kt = 0; kt < NKT; ++kt) {
        COMPUTE(kt & 1);
        int s = (kt + 1) & 1;
        if (kt + 1 < NKT) WR(s, s);          // stage k_{t+1} (loaded 2 iters ago)
        if (kt + 3 < NKT) LD(s, kt + 3);     // refill slot with k_{t+3}
        __syncthreads();
    }

    // epilogue: store raw xW as bf16
#pragma unroll
    for (int fn = 0; fn < 2; ++fn) {
        int o = w * 32 + fn * 16 + l15;
#pragma unroll
        for (int fm = 0; fm < 2; ++fm) {
#pragma unroll
            for (int r = 0; r < 4; ++r) {
                int t = t0 + fm * 16 + ksl * 4 + r;
                logits[((size_t)b * T_ + t) * OUT_ + o] = f2bf(acc[fm][fn][r]);
            }
        }
    }
}

// ---------------------------------------------------------------------------
// Kernel 2: merge — recompute seg start/cnt in-block, then
// out[b][o][s] = mean(logits over run) + bias (0 if empty), transposed store.
// ---------------------------------------------------------------------------
__global__ __launch_bounds__(256) void merge_kernel(
    const ushort* __restrict__ logits, const int* __restrict__ seg,
    const float* __restrict__ bias, float* __restrict__ out)
{
    int blk = blockIdx.x;
    int b   = blk >> 3;
    int s0  = (blk & 7) * 64;
    int tid = threadIdx.x;

    __shared__ int   sstart[64];
    __shared__ int   scnt[64];
    __shared__ float tile[OUT_][65];   // [o][sl], padded

    if (tid < 64) { sstart[tid] = T_; scnt[tid] = 0; }
    __syncthreads();
#pragma unroll
    for (int p = 0; p < 2; ++p) {
        int t = tid + p * 256;
        int li = seg[b * T_ + t] - s0;
        if (li >= 0 && li < 64) {
            atomicMin(&sstart[li], t);
            atomicAdd(&scnt[li], 1);
        }
    }
    __syncthreads();

    // compute means: consecutive lanes -> consecutive o (coalesced reads)
#pragma unroll
    for (int it = 0; it < 32; ++it) {
        int idx = tid + it * 256;     // 0..8191
        int sl  = idx >> 7;           // 0..63 (uniform per wave)
        int o   = idx & 127;
        int c   = scnt[sl];
        float v = 0.f;
        if (c > 0) {
            int st = sstart[sl];
            const ushort* src = logits + ((size_t)b * T_ + st) * OUT_ + o;
            float sum = 0.f;
            for (int i = 0; i < c; ++i) sum += bf2f(src[(size_t)i * OUT_]);
            v = sum / (float)c + bias[o];
        }
        tile[o][sl] = v;
    }
    __syncthreads();

    // transposed store: consecutive lanes -> consecutive s (coalesced writes)
#pragma unroll
    for (int p = 0; p < 32; ++p) {
        int o  = (tid >> 6) + p * 4;
        int sl = tid & 63;
        out[((size_t)b * OUT_ + o) * T_ + s0 + sl] = tile[o][sl];
    }
}

// ---------------------------------------------------------------------------
extern "C" void kernel_launch(void* const* d_in, const int* in_sizes, int n_in,
                              void* d_out, int out_size, void* d_ws, size_t ws_size,
                              hipStream_t stream) {
    const float* hs   = (const float*)d_in[0];   // (B, S, H)
    const float* W    = (const float*)d_in[1];   // (H, OUT)
    const float* bias = (const float*)d_in[2];   // (OUT,)
    const int*   seg  = (const int*)d_in[3];     // (B, T)
    float* out = (float*)d_out;                  // (B, OUT, T)

    // ws layout: logits bf16 (8.4 MB) | Wt bf16 (256 KB)
    ushort* logits = (ushort*)d_ws;
    ushort* Wt     = logits + (size_t)B_ * T_ * OUT_;

    wt_kernel<<<dim3(H_ / 64, OUT_ / 64), 256, 0, stream>>>(W, Wt);
    gemm_kernel<<<B_ * (T_ / BM), 256, 0, stream>>>(hs, Wt, logits);
    merge_kernel<<<B_ * (T_ / 64), 256, 0, stream>>>(logits, seg, bias, out);
}

// Round 11
// 64.885 us; speedup vs baseline: 1.7482x; 1.7482x over previous
//
#include <hip/hip_runtime.h>
#include <hip/hip_bf16.h>

#define B_    64
#define S_    513
#define T_    512
#define H_    1024
#define OUT_  128

#define BM 32
#define BN 128
#define BK 32
#define NKT (H_ / BK)   // 32

#define ACS 272    // A LDS chunk stride (ushorts): 544 B -> +8 banks per ksl
#define BCS 1040   // B LDS chunk stride (ushorts): 2080 B -> +8 banks per ksl

typedef __attribute__((ext_vector_type(8))) short short8_t;
typedef __attribute__((ext_vector_type(4))) float f32x4;

__device__ inline ushort f2bf(float f) {
    union { float f; unsigned u; } x; x.f = f;
    unsigned r = x.u + 0x7fffu + ((x.u >> 16) & 1u);   // RNE
    return (ushort)(r >> 16);
}
__device__ inline float bf2f(ushort u) {
    union { unsigned u; float f; } x; x.u = (unsigned)u << 16; return x.f;
}
// 4 fp32 -> 4 bf16 (RNE) via HW pack-convert
__device__ inline uint2 cvt4(const float4& v) {
    uint2 r;
    asm("v_cvt_pk_bf16_f32 %0, %1, %2" : "=v"(r.x) : "v"(v.x), "v"(v.y));
    asm("v_cvt_pk_bf16_f32 %0, %1, %2" : "=v"(r.y) : "v"(v.z), "v"(v.w));
    return r;
}

// ---------------------------------------------------------------------------
// Kernel 0: Wt[o][k] = bf16(W[k][o])  (256 KB, stays L2-resident)
// ---------------------------------------------------------------------------
__global__ __launch_bounds__(256) void wt_kernel(
    const float* __restrict__ W, ushort* __restrict__ Wt)
{
    __shared__ ushort tile[64][65];
    int k0 = blockIdx.x * 64, o0 = blockIdx.y * 64;
    int tid = threadIdx.x;
#pragma unroll
    for (int p = 0; p < 16; ++p) {
        int idx = tid + p * 256;
        int r = idx >> 6, c = idx & 63;
        tile[r][c] = f2bf(W[(size_t)(k0 + r) * OUT_ + o0 + c]);
    }
    __syncthreads();
#pragma unroll
    for (int p = 0; p < 16; ++p) {
        int idx = tid + p * 256;
        int c = idx >> 6, r = idx & 63;
        Wt[(size_t)(o0 + c) * H_ + k0 + r] = tile[r][c];
    }
}

// ---------------------------------------------------------------------------
// Kernel 1: logits(bf16) = bf16(x) @ bf16(Wt^T), raw (bias in merge).
// 32(T) x 128(OUT) tile -> grid 1024 = 4 blocks/CU, 256 thr = 4 waves,
// wave tile 32x32 (2A x 2B frags). k-major padded LDS (conflict-free b128),
// register prefetch depth 2, K-loop unrolled x2 with NAMED register sets
// (all indices compile-time -> no scratch).
// ---------------------------------------------------------------------------
__global__ __launch_bounds__(256, 4) void gemm_kernel(
    const float* __restrict__ hs, const ushort* __restrict__ Wt,
    ushort* __restrict__ logits)
{
    __shared__ __align__(16) ushort As[2][4 * ACS];   // 4.3 KB
    __shared__ __align__(16) ushort Bs[2][4 * BCS];   // 16.6 KB

    int blk = blockIdx.x;
    int b   = blk >> 4;
    int t0  = (blk & 15) * BM;
    int tid = threadIdx.x;
    int lane = tid & 63;
    int w    = tid >> 6;            // wave: cols [w*32, w*32+32)
    int l15  = lane & 15, ksl = lane >> 4;

    // A staging: thread = one float4 (4 k-elems) of one row
    int arow = tid >> 3, ac2 = tid & 7;
    const float* aptr = hs + ((size_t)(b * S_ + 1 + t0 + arow)) * H_ + ac2 * 4;
    int wAo = (ac2 >> 1) * ACS + arow * 8 + (ac2 & 1) * 4;

    // B staging: thread = 32 B (two 16B chunks) of one Wt row
    int brow = tid >> 1, bc = (tid & 1) * 2;
    const ushort* bptr = Wt + (size_t)brow * H_ + bc * 8;
    int wBo0 = bc * BCS + brow * 8;
    int wBo1 = wBo0 + BCS;

    // fragment read offsets
    int rAo[2], rBo[2];
#pragma unroll
    for (int fm = 0; fm < 2; ++fm) rAo[fm] = ksl * ACS + (fm * 16 + l15) * 8;
#pragma unroll
    for (int fn = 0; fn < 2; ++fn)
        rBo[fn] = ksl * BCS + (w * 32 + fn * 16 + l15) * 8;

    f32x4 acc[2][2];
#pragma unroll
    for (int fm = 0; fm < 2; ++fm)
#pragma unroll
        for (int fn = 0; fn < 2; ++fn) acc[fm][fn] = (f32x4){0.f, 0.f, 0.f, 0.f};

    // two NAMED register sets (compile-time indexed -> stay in VGPRs)
    float4 raA, raB;
    int4   rb0A, rb1A, rb0B, rb1B;

#define LD_A(kt) { const float* ap = aptr + (kt) * BK;                        \
                   raA  = *reinterpret_cast<const float4*>(ap);               \
                   const ushort* bp = bptr + (kt) * BK;                       \
                   rb0A = *reinterpret_cast<const int4*>(bp);                 \
                   rb1A = *reinterpret_cast<const int4*>(bp + 8); }
#define LD_B(kt) { const float* ap = aptr + (kt) * BK;                        \
                   raB  = *reinterpret_cast<const float4*>(ap);               \
                   const ushort* bp = bptr + (kt) * BK;                       \
                   rb0B = *reinterpret_cast<const int4*>(bp);                 \
                   rb1B = *reinterpret_cast<const int4*>(bp + 8); }
#define WR_A(nb) { *reinterpret_cast<uint2*>(&As[nb][wAo]) = cvt4(raA);       \
                   *reinterpret_cast<int4*>(&Bs[nb][wBo0]) = rb0A;            \
                   *reinterpret_cast<int4*>(&Bs[nb][wBo1]) = rb1A; }
#define WR_B(nb) { *reinterpret_cast<uint2*>(&As[nb][wAo]) = cvt4(raB);       \
                   *reinterpret_cast<int4*>(&Bs[nb][wBo0]) = rb0B;            \
                   *reinterpret_cast<int4*>(&Bs[nb][wBo1]) = rb1B; }

    auto COMPUTE = [&](int cb) {
        short8_t af[2], bf[2];
#pragma unroll
        for (int fm = 0; fm < 2; ++fm)
            af[fm] = *reinterpret_cast<const short8_t*>(&As[cb][rAo[fm]]);
#pragma unroll
        for (int fn = 0; fn < 2; ++fn)
            bf[fn] = *reinterpret_cast<const short8_t*>(&Bs[cb][rBo[fn]]);
#pragma unroll
        for (int fm = 0; fm < 2; ++fm)
#pragma unroll
            for (int fn = 0; fn < 2; ++fn)
                acc[fm][fn] = __builtin_amdgcn_mfma_f32_16x16x32_bf16(
                    af[fm], bf[fn], acc[fm][fn], 0, 0, 0);
    };

    // prologue: A=k0, B=k1; stage k0 -> buf0; A refilled with k2
    LD_A(0); LD_B(1);
    WR_A(0);
    __syncthreads();
    LD_A(2);

#pragma unroll 1
    for (int kt = 0; kt < NKT; kt += 2) {
        COMPUTE(0);                      // buf0 = k_kt
        if (kt + 1 < NKT) WR_B(1);       // stage k_{kt+1}
        if (kt + 3 < NKT) LD_B(kt + 3);  // B <- k_{kt+3}
        __syncthreads();
        COMPUTE(1);                      // buf1 = k_{kt+1}
        if (kt + 2 < NKT) WR_A(0);       // stage k_{kt+2}
        if (kt + 4 < NKT) LD_A(kt + 4);  // A <- k_{kt+4}
        __syncthreads();
    }
#undef LD_A
#undef LD_B
#undef WR_A
#undef WR_B

    // epilogue: store raw xW as bf16
#pragma unroll
    for (int fn = 0; fn < 2; ++fn) {
        int o = w * 32 + fn * 16 + l15;
#pragma unroll
        for (int fm = 0; fm < 2; ++fm) {
#pragma unroll
            for (int r = 0; r < 4; ++r) {
                int t = t0 + fm * 16 + ksl * 4 + r;
                logits[((size_t)b * T_ + t) * OUT_ + o] = f2bf(acc[fm][fn][r]);
            }
        }
    }
}

// ---------------------------------------------------------------------------
// Kernel 2: merge — recompute seg start/cnt in-block, then
// out[b][o][s] = mean(logits over run) + bias (0 if empty), transposed store.
// ---------------------------------------------------------------------------
__global__ __launch_bounds__(256) void merge_kernel(
    const ushort* __restrict__ logits, const int* __restrict__ seg,
    const float* __restrict__ bias, float* __restrict__ out)
{
    int blk = blockIdx.x;
    int b   = blk >> 3;
    int s0  = (blk & 7) * 64;
    int tid = threadIdx.x;

    __shared__ int   sstart[64];
    __shared__ int   scnt[64];
    __shared__ float tile[OUT_][65];   // [o][sl], padded

    if (tid < 64) { sstart[tid] = T_; scnt[tid] = 0; }
    __syncthreads();
#pragma unroll
    for (int p = 0; p < 2; ++p) {
        int t = tid + p * 256;
        int li = seg[b * T_ + t] - s0;
        if (li >= 0 && li < 64) {
            atomicMin(&sstart[li], t);
            atomicAdd(&scnt[li], 1);
        }
    }
    __syncthreads();

    // compute means: consecutive lanes -> consecutive o (coalesced reads)
#pragma unroll
    for (int it = 0; it < 32; ++it) {
        int idx = tid + it * 256;     // 0..8191
        int sl  = idx >> 7;           // 0..63 (uniform per wave)
        int o   = idx & 127;
        int c   = scnt[sl];
        float v = 0.f;
        if (c > 0) {
            int st = sstart[sl];
            const ushort* src = logits + ((size_t)b * T_ + st) * OUT_ + o;
            float sum = 0.f;
            for (int i = 0; i < c; ++i) sum += bf2f(src[(size_t)i * OUT_]);
            v = sum / (float)c + bias[o];
        }
        tile[o][sl] = v;
    }
    __syncthreads();

    // transposed store: consecutive lanes -> consecutive s (coalesced writes)
#pragma unroll
    for (int p = 0; p < 32; ++p) {
        int o  = (tid >> 6) + p * 4;
        int sl = tid & 63;
        out[((size_t)b * OUT_ + o) * T_ + s0 + sl] = tile[o][sl];
    }
}

// ---------------------------------------------------------------------------
extern "C" void kernel_launch(void* const* d_in, const int* in_sizes, int n_in,
                              void* d_out, int out_size, void* d_ws, size_t ws_size,
                              hipStream_t stream) {
    const float* hs   = (const float*)d_in[0];   // (B, S, H)
    const float* W    = (const float*)d_in[1];   // (H, OUT)
    const float* bias = (const float*)d_in[2];   // (OUT,)
    const int*   seg  = (const int*)d_in[3];     // (B, T)
    float* out = (float*)d_out;                  // (B, OUT, T)

    // ws layout: logits bf16 (8.4 MB) | Wt bf16 (256 KB)
    ushort* logits = (ushort*)d_ws;
    ushort* Wt     = logits + (size_t)B_ * T_ * OUT_;

    wt_kernel<<<dim3(H_ / 64, OUT_ / 64), 256, 0, stream>>>(W, Wt);
    gemm_kernel<<<B_ * (T_ / BM), 256, 0, stream>>>(hs, Wt, logits);
    merge_kernel<<<B_ * (T_ / 64), 256, 0, stream>>>(logits, seg, bias, out);
}